// Round 1
// baseline (314.070 us; speedup 1.0000x reference)
//
#include <hip/hip_runtime.h>

#define DD 256      // embed dim
#define NH 8        // heads
#define HDm 32      // head dim
#define NP 1024     // patches
#define NE 256      // experts
#define NQ 64       // query embeddings
#define INV_SQRT_HD 0.17677669529663687f

__device__ __forceinline__ float wred_sum(float p) {
  #pragma unroll
  for (int m = 32; m; m >>= 1) p += __shfl_xor(p, m);
  return p;
}
__device__ __forceinline__ float wred_max(float p) {
  #pragma unroll
  for (int m = 32; m; m >>= 1) p = fmaxf(p, __shfl_xor(p, m));
  return p;
}
__device__ __forceinline__ float rdlane(float v, int l) {
  return __int_as_float(__builtin_amdgcn_readlane(__float_as_int(v), l));
}
__device__ __forceinline__ float dot4(float4 a, float4 b) {
  return a.x*b.x + a.y*b.y + a.z*b.z + a.w*b.w;
}

// mean/var layernorm over a 256-float LDS buffer; writes out[tid] for tid<256
__device__ __forceinline__ void layernorm_store(const float* buf, float* outp,
                                                const float* g, const float* b,
                                                float* red, int tid, int wid, int lane)
{
  __syncthreads();
  if (wid == 0) {
    float s = buf[lane] + buf[lane+64] + buf[lane+128] + buf[lane+192];
    s = wred_sum(s);
    if (!lane) red[0] = s * (1.f/256.f);
  }
  __syncthreads();
  float mn = red[0];
  if (wid == 0) {
    float d0 = buf[lane]-mn, d1 = buf[lane+64]-mn, d2 = buf[lane+128]-mn, d3 = buf[lane+192]-mn;
    float s = d0*d0 + d1*d1 + d2*d2 + d3*d3;
    s = wred_sum(s);
    if (!lane) red[1] = rsqrtf(s * (1.f/256.f) + 1e-5f);
  }
  __syncthreads();
  if (tid < 256) outp[tid] = (buf[tid] - mn) * red[1] * g[tid] + b[tid];
}

// ---------------- patches transpose: pT[c][p] = patches[p][c] ----------------
__global__ __launch_bounds__(256)
void k_transpose(const float* __restrict__ in, float* __restrict__ out)
{
  __shared__ float tile[32][33];
  const int pb = blockIdx.x*32, cb = blockIdx.y*32;
  const int tx = threadIdx.x, ty = threadIdx.y; // 32 x 8
  #pragma unroll
  for (int i = 0; i < 4; ++i)
    tile[ty + i*8][tx] = in[(size_t)(pb + ty + i*8)*DD + cb + tx];
  __syncthreads();
  #pragma unroll
  for (int i = 0; i < 4; ++i)
    out[(size_t)(cb + ty + i*8)*NP + pb + tx] = tile[tx][ty + i*8];
}

// ---------------- K/V projection of query_embeddings ----------------
// kvq[j][r] = dot(qe[j,:], Wqkv_q[256+r,:]) + bqkv_q[256+r],  r in [0,512)
__global__ __launch_bounds__(512)
void k_kvq(const float* __restrict__ qe, const float* __restrict__ Wqkv_q,
           const float* __restrict__ bqkv_q, float* __restrict__ kvq)
{
  const int j = blockIdx.x, tid = threadIdx.x, wid = tid>>6, lane = tid&63;
  __shared__ float x[DD];
  if (tid < DD) x[tid] = qe[j*DD + tid];
  __syncthreads();
  float4 x4 = *(const float4*)&x[4*lane];
  #pragma unroll 2
  for (int cnt = 0; cnt < 64; ++cnt) {
    int r = wid*64 + cnt;
    float4 w4 = *(const float4*)&Wqkv_q[(size_t)(DD + r)*DD + 4*lane];
    float p = wred_sum(dot4(w4, x4));
    if (!lane) kvq[j*512 + r] = p + bqkv_q[DD + r];
  }
}

// ---------------- per-expert cross attention + LN1 ----------------
__global__ __launch_bounds__(512)
void k_expert(const float* __restrict__ patches, const float* __restrict__ pT,
              const float* __restrict__ et_g, const float* __restrict__ Wqkv,
              const float* __restrict__ bqkv, const float* __restrict__ Wo,
              const float* __restrict__ bo, const float* __restrict__ ln1g,
              const float* __restrict__ ln1b, float* __restrict__ aln,
              float* __restrict__ iaw)
{
  const int n = blockIdx.x;
  const int tid = threadIdx.x, wid = tid >> 6, lane = tid & 63;
  __shared__ float et[DD], qv[DD], qb[NH], rinvS[NH];
  __shared__ float tS[NH][DD];
  __shared__ float attS[NH][NP];
  __shared__ float uS[NH][DD];
  __shared__ float ctxS[DD], resS[DD], red[2];

  const float* Wn = Wqkv + (size_t)n * (3*DD*DD);
  const float* bn = bqkv + (size_t)n * (3*DD);

  if (tid < DD) et[tid] = et_g[n*DD + tid];
  for (int i = tid; i < NH*DD; i += 512) (&uS[0][0])[i] = 0.f;
  __syncthreads();

  // P1: q[e] = sum_d et[d]*Wq[e,d] + bq[e]   (wave-per-row)
  {
    float4 x4 = *(const float4*)&et[4*lane];
    #pragma unroll 2
    for (int cnt = 0; cnt < 32; ++cnt) {
      int e = wid*32 + cnt;
      float4 w4 = *(const float4*)&Wn[(size_t)e*DD + 4*lane];
      float p = wred_sum(dot4(w4, x4));
      if (!lane) qv[e] = p + bn[e];
    }
  }
  __syncthreads();

  // qb[h] = q_h . bk_h  (softmax-invariant but kept for exactness)
  if (tid < NH) {
    float s = 0.f;
    for (int d = 0; d < HDm; ++d) s += qv[tid*HDm + d] * bn[DD + tid*HDm + d];
    qb[tid] = s;
  }

  // P2: t[h][c] = sum_d qv[h*32+d] * Wk[h*32+d][c]   (wave == head)
  {
    const int h = wid;
    float4 acc = make_float4(0.f,0.f,0.f,0.f);
    #pragma unroll 4
    for (int d = 0; d < HDm; ++d) {
      float4 w4 = *(const float4*)&Wn[(size_t)(DD + h*HDm + d)*DD + 4*lane];
      float q = qv[h*HDm + d];
      acc.x += q*w4.x; acc.y += q*w4.y; acc.z += q*w4.z; acc.w += q*w4.w;
    }
    *(float4*)&tS[h][4*lane] = acc;
  }
  __syncthreads();

  // P3: scores s[h][p] = (t[h,:].patches[p,:] + qb[h]) * inv_sqrt_hd
  // waves 0..3 each own a 256-patch quarter, all 8 heads; t held in registers.
  if (wid < 4) {
    const int pb = wid*256;
    float treg[32];
    #pragma unroll
    for (int k = 0; k < 32; ++k) treg[k] = tS[k & 7][(k >> 3)*64 + lane];
    float4 sacc[8];
    #pragma unroll
    for (int h = 0; h < 8; ++h) sacc[h] = make_float4(0.f,0.f,0.f,0.f);
    const float* pbase = pT + pb + 4*lane;
    #pragma unroll
    for (int cb = 0; cb < 4; ++cb) {
      #pragma unroll 8
      for (int c0 = 0; c0 < 64; ++c0) {
        float4 pv = *(const float4*)&pbase[(size_t)(cb*64 + c0)*NP];
        #pragma unroll
        for (int h = 0; h < 8; ++h) {
          float tv = rdlane(treg[cb*8 + h], c0);
          sacc[h].x += tv*pv.x; sacc[h].y += tv*pv.y;
          sacc[h].z += tv*pv.z; sacc[h].w += tv*pv.w;
        }
      }
    }
    #pragma unroll
    for (int h = 0; h < 8; ++h) {
      float qbh = qb[h];
      float4 o;
      o.x = (sacc[h].x + qbh) * INV_SQRT_HD;
      o.y = (sacc[h].y + qbh) * INV_SQRT_HD;
      o.z = (sacc[h].z + qbh) * INV_SQRT_HD;
      o.w = (sacc[h].w + qbh) * INV_SQRT_HD;
      *(float4*)&attS[h][pb + 4*lane] = o;
    }
  }
  __syncthreads();

  // P4: softmax over p per head (wave == head); store unnormalized exp + 1/sum
  {
    const int h = wid;
    float v[16];
    #pragma unroll
    for (int k = 0; k < 16; ++k) v[k] = attS[h][k*64 + lane];
    float mx = v[0];
    #pragma unroll
    for (int k = 1; k < 16; ++k) mx = fmaxf(mx, v[k]);
    mx = wred_max(mx);
    float sum = 0.f;
    #pragma unroll
    for (int k = 0; k < 16; ++k) {
      v[k] = __expf(v[k] - mx);
      sum += v[k];
      attS[h][k*64 + lane] = v[k];
    }
    sum = wred_sum(sum);
    if (!lane) rinvS[h] = 1.f / sum;
  }
  __syncthreads();

  // P6 (waves 0-3): u[h][c] = sum_p att[h][p]*patches[p][c]  ||  P5 (waves 4-7): head-mean -> iaw
  if (wid < 4) {
    const int pb = wid*256;
    float areg[32];
    #pragma unroll
    for (int k = 0; k < 32; ++k)
      areg[k] = attS[k & 7][pb + (k >> 3)*64 + lane] * rinvS[k & 7];
    float4 up[8];
    #pragma unroll
    for (int h = 0; h < 8; ++h) up[h] = make_float4(0.f,0.f,0.f,0.f);
    const float* pbase = patches + (size_t)pb*DD + 4*lane;
    #pragma unroll
    for (int pb2 = 0; pb2 < 4; ++pb2) {
      #pragma unroll 8
      for (int p0 = 0; p0 < 64; ++p0) {
        float4 pv = *(const float4*)&pbase[(size_t)(pb2*64 + p0)*DD];
        #pragma unroll
        for (int h = 0; h < 8; ++h) {
          float a = rdlane(areg[pb2*8 + h], p0);
          up[h].x += a*pv.x; up[h].y += a*pv.y; up[h].z += a*pv.z; up[h].w += a*pv.w;
        }
      }
    }
    #pragma unroll
    for (int h = 0; h < 8; ++h) {
      atomicAdd(&uS[h][4*lane+0], up[h].x);
      atomicAdd(&uS[h][4*lane+1], up[h].y);
      atomicAdd(&uS[h][4*lane+2], up[h].z);
      atomicAdd(&uS[h][4*lane+3], up[h].w);
    }
  } else {
    const int t2 = tid - 256;
    #pragma unroll
    for (int k = 0; k < 4; ++k) {
      int p = k*256 + t2;
      float s = 0.f;
      #pragma unroll
      for (int h = 0; h < 8; ++h) s += attS[h][p] * rinvS[h];
      iaw[(size_t)n*NP + p] = s * 0.125f;
    }
  }
  __syncthreads();

  // P7: ctx[r] = u[h].Wv[r,:] + bv[r]   (wave wid handles rows wid*32.. => single h)
  {
    const int h = wid;
    float4 u4 = *(const float4*)&uS[h][4*lane];
    #pragma unroll 2
    for (int cnt = 0; cnt < 32; ++cnt) {
      int r = wid*32 + cnt;
      float4 w4 = *(const float4*)&Wn[(size_t)(2*DD + r)*DD + 4*lane];
      float p = wred_sum(dot4(w4, u4));
      if (!lane) ctxS[r] = p + bn[2*DD + r];
    }
  }
  __syncthreads();

  // P8: attended[e] = ctx.Wo[e,:] + bo[e] + residual et[e]
  {
    float4 c4 = *(const float4*)&ctxS[4*lane];
    const float* Won = Wo + (size_t)n*DD*DD;
    #pragma unroll 2
    for (int cnt = 0; cnt < 32; ++cnt) {
      int e = wid*32 + cnt;
      float4 w4 = *(const float4*)&Won[(size_t)e*DD + 4*lane];
      float p = wred_sum(dot4(w4, c4));
      if (!lane) resS[e] = p + bo[n*DD + e] + et[e];
    }
  }
  // P9: LN1 -> aln
  layernorm_store(resS, aln + (size_t)n*DD, ln1g, ln1b, red, tid, wid, lane);
}

// ---------------- query cross attention + LN2 (one WG per expert row) ----------------
__global__ __launch_bounds__(512)
void k_qca(const float* __restrict__ aln, const float* __restrict__ kvq,
           const float* __restrict__ Wqkv_q, const float* __restrict__ bqkv_q,
           const float* __restrict__ Wo_q, const float* __restrict__ bo_q,
           const float* __restrict__ ln2g, const float* __restrict__ ln2b,
           float* __restrict__ aq)
{
  const int i = blockIdx.x, tid = threadIdx.x, wid = tid>>6, lane = tid&63;
  __shared__ float x[DD], qr[DD], attq[NH][NQ], ctxv[DD], y[DD], red[2];
  if (tid < DD) x[tid] = aln[(size_t)i*DD + tid];
  __syncthreads();
  // q projection
  {
    float4 x4 = *(const float4*)&x[4*lane];
    #pragma unroll 2
    for (int cnt = 0; cnt < 32; ++cnt) {
      int e = wid*32 + cnt;
      float4 w4 = *(const float4*)&Wqkv_q[(size_t)e*DD + 4*lane];
      float p = wred_sum(dot4(w4, x4));
      if (!lane) qr[e] = p + bqkv_q[e];
    }
  }
  __syncthreads();
  // scores + softmax: wave == head, lane == kv index j
  {
    const int h = wid, j = lane;
    const float* kj = kvq + (size_t)j*512 + h*HDm;
    float s = 0.f;
    #pragma unroll
    for (int m = 0; m < 8; ++m) {
      float4 k4 = *(const float4*)&kj[4*m];
      float4 q4 = *(const float4*)&qr[h*HDm + 4*m];
      s += dot4(k4, q4);
    }
    s *= INV_SQRT_HD;
    float mx = wred_max(s);
    float p = __expf(s - mx);
    float sum = wred_sum(p);
    attq[h][j] = p / sum;
  }
  __syncthreads();
  // ctx
  if (tid < DD) {
    const int rr = tid, h = rr >> 5;
    float acc = 0.f;
    #pragma unroll 4
    for (int j4 = 0; j4 < 16; ++j4) {
      float4 a4 = *(const float4*)&attq[h][j4*4];
      acc += a4.x * kvq[(size_t)(j4*4+0)*512 + DD + rr]
           + a4.y * kvq[(size_t)(j4*4+1)*512 + DD + rr]
           + a4.z * kvq[(size_t)(j4*4+2)*512 + DD + rr]
           + a4.w * kvq[(size_t)(j4*4+3)*512 + DD + rr];
    }
    ctxv[rr] = acc;
  }
  __syncthreads();
  // out proj + residual
  {
    float4 c4 = *(const float4*)&ctxv[4*lane];
    #pragma unroll 2
    for (int cnt = 0; cnt < 32; ++cnt) {
      int e = wid*32 + cnt;
      float4 w4 = *(const float4*)&Wo_q[(size_t)e*DD + 4*lane];
      float p = wred_sum(dot4(w4, c4));
      if (!lane) y[e] = p + bo_q[e] + x[e];
    }
  }
  layernorm_store(y, aq + (size_t)i*DD, ln2g, ln2b, red, tid, wid, lane);
}

// ---------------- generic 32x32-tile f32 GEMM: out = X[M,K] @ W[N,K]^T (+bias, relu) ----------------
// processes K-chunk [blockIdx.z*256, +256); out offset by z*M*NC (split-K partials)
__global__ __launch_bounds__(256)
void k_gemm32(const float* __restrict__ X, const float* __restrict__ W,
              const float* __restrict__ bias, float* __restrict__ out,
              int ldk, int NC, int relu)
{
  __shared__ float Xs[32][256], Ws[32][256];
  const int tid = threadIdx.x;
  const int ib = blockIdx.x*32, cb = blockIdx.y*32;
  const int kb = blockIdx.z*256;
  const int col = tid & 31, rg = tid >> 5;
  for (int idx = tid*4; idx < 32*256; idx += 1024) {
    int r = idx >> 8, c = idx & 255;
    *(float4*)&Xs[r][c] = *(const float4*)&X[(size_t)(ib + r)*ldk + kb + c];
    int cs = ((c >> 2) ^ (r & 7)) << 2;           // XOR swizzle: conflict-free b128 reads
    *(float4*)&Ws[r][cs] = *(const float4*)&W[(size_t)(cb + r)*ldk + kb + c];
  }
  __syncthreads();
  float a0=0.f, a1=0.f, a2=0.f, a3=0.f;
  #pragma unroll 16
  for (int d4 = 0; d4 < 64; ++d4) {
    float4 w4 = *(const float4*)&Ws[col][((d4 ^ (col & 7)) << 2)];
    float4 x0 = *(const float4*)&Xs[rg*4+0][d4<<2];
    float4 x1 = *(const float4*)&Xs[rg*4+1][d4<<2];
    float4 x2 = *(const float4*)&Xs[rg*4+2][d4<<2];
    float4 x3 = *(const float4*)&Xs[rg*4+3][d4<<2];
    a0 += dot4(w4,x0); a1 += dot4(w4,x1); a2 += dot4(w4,x2); a3 += dot4(w4,x3);
  }
  float bv = bias ? bias[cb + col] : 0.f;
  float o0=a0+bv, o1=a1+bv, o2=a2+bv, o3=a3+bv;
  if (relu) { o0=fmaxf(o0,0.f); o1=fmaxf(o1,0.f); o2=fmaxf(o2,0.f); o3=fmaxf(o3,0.f); }
  out += (size_t)blockIdx.z * ((size_t)gridDim.x * 32 * NC);
  size_t rb = (size_t)(ib + rg*4)*NC + cb + col;
  out[rb] = o0; out[rb + NC] = o1; out[rb + 2*(size_t)NC] = o2; out[rb + 3*(size_t)NC] = o3;
}

// sum 4 split-K partials + bias(b2)
__global__ __launch_bounds__(256)
void k_red(const float* __restrict__ part, const float* __restrict__ b2, float* __restrict__ er)
{
  int idx = blockIdx.x*256 + threadIdx.x;
  er[idx] = part[idx] + part[65536+idx] + part[131072+idx] + part[196608+idx] + b2[idx & 255];
}

// ---------------- self attention + LN3 (one WG per expert row) ----------------
__global__ __launch_bounds__(512)
void k_sa(const float* __restrict__ er, const float* __restrict__ qkvs,
          const float* __restrict__ Wo_s, const float* __restrict__ bo_s,
          const float* __restrict__ ln3g, const float* __restrict__ ln3b,
          float* __restrict__ ef)
{
  const int i = blockIdx.x, tid = threadIdx.x, wid = tid>>6, lane = tid&63;
  __shared__ float x[DD], qr[DD], attl[NH][NE], ctxv[DD], y[DD], red[2];
  if (tid < DD) { x[tid] = er[(size_t)i*DD + tid]; qr[tid] = qkvs[(size_t)i*768 + tid]; }
  __syncthreads();
  // scores: wave == head; 4 key reps per lane
  {
    const int h = wid;
    float4 q4[8];
    #pragma unroll
    for (int m = 0; m < 8; ++m) q4[m] = *(const float4*)&qr[h*HDm + 4*m];
    #pragma unroll
    for (int rep = 0; rep < 4; ++rep) {
      int j = lane + 64*rep;
      const float* kj = qkvs + (size_t)j*768 + DD + h*HDm;
      float s = 0.f;
      #pragma unroll
      for (int m = 0; m < 8; ++m) {
        float4 k4 = *(const float4*)&kj[4*m];
        s += dot4(k4, q4[m]);
      }
      attl[h][j] = s * INV_SQRT_HD;
    }
  }
  __syncthreads();
  // softmax over 256 keys (wave == head)
  {
    const int h = wid;
    float v0 = attl[h][lane], v1 = attl[h][lane+64], v2 = attl[h][lane+128], v3 = attl[h][lane+192];
    float mx = wred_max(fmaxf(fmaxf(v0,v1), fmaxf(v2,v3)));
    float e0 = __expf(v0-mx), e1 = __expf(v1-mx), e2 = __expf(v2-mx), e3 = __expf(v3-mx);
    float sum = wred_sum(e0+e1+e2+e3);
    float r = 1.f/sum;
    attl[h][lane] = e0*r; attl[h][lane+64] = e1*r; attl[h][lane+128] = e2*r; attl[h][lane+192] = e3*r;
  }
  __syncthreads();
  // ctx
  if (tid < DD) {
    const int rr = tid, h = rr >> 5;
    float acc = 0.f;
    for (int j4 = 0; j4 < 64; ++j4) {
      float4 a4 = *(const float4*)&attl[h][j4*4];
      acc += a4.x * qkvs[(size_t)(j4*4+0)*768 + 512 + rr]
           + a4.y * qkvs[(size_t)(j4*4+1)*768 + 512 + rr]
           + a4.z * qkvs[(size_t)(j4*4+2)*768 + 512 + rr]
           + a4.w * qkvs[(size_t)(j4*4+3)*768 + 512 + rr];
    }
    ctxv[rr] = acc;
  }
  __syncthreads();
  // out proj + residual
  {
    float4 c4 = *(const float4*)&ctxv[4*lane];
    #pragma unroll 2
    for (int cnt = 0; cnt < 32; ++cnt) {
      int e = wid*32 + cnt;
      float4 w4 = *(const float4*)&Wo_s[(size_t)e*DD + 4*lane];
      float p = wred_sum(dot4(w4, c4));
      if (!lane) y[e] = p + bo_s[e] + x[e];
    }
  }
  layernorm_store(y, ef + (size_t)i*DD, ln3g, ln3b, red, tid, wid, lane);
}

extern "C" void kernel_launch(void* const* d_in, const int* in_sizes, int n_in,
                              void* d_out, int out_size, void* d_ws, size_t ws_size,
                              hipStream_t stream) {
  const float* patches = (const float*)d_in[0];
  const float* et      = (const float*)d_in[1];
  const float* qe      = (const float*)d_in[2];
  const float* Wqkv_e  = (const float*)d_in[3];
  const float* bqkv_e  = (const float*)d_in[4];
  const float* Wo_e    = (const float*)d_in[5];
  const float* bo_e    = (const float*)d_in[6];
  const float* Wqkv_q  = (const float*)d_in[7];
  const float* bqkv_q  = (const float*)d_in[8];
  const float* Wo_q    = (const float*)d_in[9];
  const float* bo_q    = (const float*)d_in[10];
  const float* Wqkv_s  = (const float*)d_in[11];
  const float* bqkv_s  = (const float*)d_in[12];
  const float* Wo_s    = (const float*)d_in[13];
  const float* bo_s    = (const float*)d_in[14];
  const float* W1      = (const float*)d_in[15];
  const float* b1      = (const float*)d_in[16];
  const float* W2      = (const float*)d_in[17];
  const float* b2      = (const float*)d_in[18];
  const float* ln1g = (const float*)d_in[19]; const float* ln1b = (const float*)d_in[20];
  const float* ln2g = (const float*)d_in[21]; const float* ln2b = (const float*)d_in[22];
  const float* ln3g = (const float*)d_in[23]; const float* ln3b = (const float*)d_in[24];

  float* ef  = (float*)d_out;               // [256*256] expert_features
  float* iaw = (float*)d_out + 65536;       // [256*1024] image_attention_weights

  float* ws    = (float*)d_ws;
  float* pT    = ws;                  // 262144
  float* aln   = ws + 262144;         // 65536
  float* kvq   = ws + 327680;         // 32768
  float* aq    = ws + 360448;         // 65536
  float* hbuf  = ws + 425984;         // 262144
  float* fpart = ws + 688128;         // 262144 (4 x 65536 split-K partials)
  float* er    = ws + 950272;         // 65536
  float* qkvs  = ws + 1015808;        // 196608

  k_transpose<<<dim3(32, 8), dim3(32, 8), 0, stream>>>(patches, pT);
  k_kvq<<<64, 512, 0, stream>>>(qe, Wqkv_q, bqkv_q, kvq);
  k_expert<<<256, 512, 0, stream>>>(patches, pT, et, Wqkv_e, bqkv_e, Wo_e, bo_e,
                                    ln1g, ln1b, aln, iaw);
  k_qca<<<256, 512, 0, stream>>>(aln, kvq, Wqkv_q, bqkv_q, Wo_q, bo_q, ln2g, ln2b, aq);
  k_gemm32<<<dim3(8, 32, 1), 256, 0, stream>>>(aq, W1, b1, hbuf, 256, 1024, 1);
  k_gemm32<<<dim3(8, 8, 4), 256, 0, stream>>>(hbuf, W2, nullptr, fpart, 1024, 256, 0);
  k_red<<<256, 256, 0, stream>>>(fpart, b2, er);
  k_gemm32<<<dim3(8, 24, 1), 256, 0, stream>>>(er, Wqkv_s, bqkv_s, qkvs, 256, 768, 0);
  k_sa<<<256, 512, 0, stream>>>(er, qkvs, Wo_s, bo_s, ln3g, ln3b, ef);
}

// Round 2
// 307.826 us; speedup vs baseline: 1.0203x; 1.0203x over previous
//
#include <hip/hip_runtime.h>

#define DD 256      // embed dim
#define NH 8        // heads
#define NP 1024     // patches
#define NQ 64       // query embeddings
#define SCALE 0.17677669529663687f

__device__ __forceinline__ float wred_sum(float p) {
  #pragma unroll
  for (int m = 32; m; m >>= 1) p += __shfl_xor(p, m);
  return p;
}
__device__ __forceinline__ float wred_max(float p) {
  #pragma unroll
  for (int m = 32; m; m >>= 1) p = fmaxf(p, __shfl_xor(p, m));
  return p;
}
// 3-level reduce within each 8-lane group (xor 1,2,4 -> DPP, no LDS)
__device__ __forceinline__ float red8(float p) {
  p += __shfl_xor(p, 1);
  p += __shfl_xor(p, 2);
  p += __shfl_xor(p, 4);
  return p;
}
__device__ __forceinline__ float rdlane(float v, int l) {
  return __int_as_float(__builtin_amdgcn_readlane(__float_as_int(v), l));
}
__device__ __forceinline__ float dot4(float4 a, float4 b) {
  return a.x*b.x + a.y*b.y + a.z*b.z + a.w*b.w;
}

// preload a 256-float LDS vector as 8 float4 fragments for the 8-lane-group scheme
__device__ __forceinline__ void preload8(const float* x, int lane, float4* xf) {
  const int o = (lane & 7) * 4;
  #pragma unroll
  for (int cc = 0; cc < 8; ++cc) xf[cc] = *(const float4*)&x[cc*32 + o];
}
// 8 rows per pass: lane's row = r0 + (lane>>3); 8 loads in flight; returns row-dot
// (sum replicated across each 8-lane group)
__device__ __forceinline__ float pass8(const float* __restrict__ W, int ldk,
                                       int r0, int lane, const float4* xf) {
  const float* base = W + (size_t)(r0 + (lane >> 3))*ldk + (lane & 7)*4;
  float4 w[8];
  #pragma unroll
  for (int cc = 0; cc < 8; ++cc) w[cc] = *(const float4*)&base[cc*32];
  float a = 0.f;
  #pragma unroll
  for (int cc = 0; cc < 8; ++cc) a += dot4(w[cc], xf[cc]);
  return red8(a);
}

// mean/var layernorm over a 256-float LDS buffer; writes outp[tid] for tid<256
__device__ __forceinline__ void layernorm_store(const float* buf, float* outp,
                                                const float* g, const float* b,
                                                float* red, int tid, int wid, int lane)
{
  __syncthreads();
  if (wid == 0) {
    float s = buf[lane] + buf[lane+64] + buf[lane+128] + buf[lane+192];
    s = wred_sum(s);
    if (!lane) red[0] = s * (1.f/256.f);
  }
  __syncthreads();
  float mn = red[0];
  if (wid == 0) {
    float d0 = buf[lane]-mn, d1 = buf[lane+64]-mn, d2 = buf[lane+128]-mn, d3 = buf[lane+192]-mn;
    float s = d0*d0 + d1*d1 + d2*d2 + d3*d3;
    s = wred_sum(s);
    if (!lane) red[1] = rsqrtf(s * (1.f/256.f) + 1e-5f);
  }
  __syncthreads();
  if (tid < 256) outp[tid] = (buf[tid] - mn) * red[1] * g[tid] + b[tid];
}

// ---------------- patches transpose: pT[c][p] = patches[p][c] ----------------
__global__ __launch_bounds__(256)
void k_transpose(const float* __restrict__ in, float* __restrict__ out)
{
  __shared__ float tile[32][33];
  const int pb = blockIdx.x*32, cb = blockIdx.y*32;
  const int tx = threadIdx.x, ty = threadIdx.y; // 32 x 8
  #pragma unroll
  for (int i = 0; i < 4; ++i)
    tile[ty + i*8][tx] = in[(size_t)(pb + ty + i*8)*DD + cb + tx];
  __syncthreads();
  #pragma unroll
  for (int i = 0; i < 4; ++i)
    out[(size_t)(cb + ty + i*8)*NP + pb + tx] = tile[tx][ty + i*8];
}

// ---------------- K/V projection of query_embeddings ----------------
__global__ __launch_bounds__(512)
void k_kvq(const float* __restrict__ qe, const float* __restrict__ Wqkv_q,
           const float* __restrict__ bqkv_q, float* __restrict__ kvq)
{
  const int j = blockIdx.x, tid = threadIdx.x, w = tid>>6, lane = tid&63;
  __shared__ float x[DD], kvrow[512];
  if (tid < DD) x[tid] = qe[j*DD + tid];
  __syncthreads();
  float4 xf[8]; preload8(x, lane, xf);
  #pragma unroll
  for (int pp = 0; pp < 8; ++pp) {
    int r0 = w*64 + pp*8;
    float a = pass8(Wqkv_q + (size_t)DD*DD, DD, r0, lane, xf);
    int r = r0 + (lane >> 3);
    if ((lane & 7) == 0) kvrow[r] = a + bqkv_q[DD + r];
  }
  __syncthreads();
  kvq[(size_t)j*512 + tid] = kvrow[tid];
}

// ---------------- fused: per-expert cross-attn + LN1 + qca + LN2 + FFN + qkv_s proj ----------------
__global__ __launch_bounds__(512)
void k_fused(const float* __restrict__ patches, const float* __restrict__ pT,
             const float* __restrict__ et_g, const float* __restrict__ Wqkv,
             const float* __restrict__ bqkv, const float* __restrict__ Wo,
             const float* __restrict__ bo,
             const float* __restrict__ kvq,
             const float* __restrict__ Wqkv_q, const float* __restrict__ bqkv_q,
             const float* __restrict__ Wo_q, const float* __restrict__ bo_q,
             const float* __restrict__ Wqkv_s, const float* __restrict__ bqkv_s,
             const float* __restrict__ W1, const float* __restrict__ b1,
             const float* __restrict__ W2, const float* __restrict__ b2,
             const float* __restrict__ ln1g, const float* __restrict__ ln1b,
             const float* __restrict__ ln2g, const float* __restrict__ ln2b,
             float* __restrict__ er_g, float* __restrict__ qkvs_g,
             float* __restrict__ iaw)
{
  const int n = blockIdx.x, tid = threadIdx.x, w = tid >> 6, lane = tid & 63;
  __shared__ float et[DD], qv[DD], qb8[NH], rinv8[NH], red2[2];
  __shared__ float tS[NH][DD];        // later reused as FFN hidden h[1024]
  __shared__ float attS[NH][NP];      // later reused as qkv row [768]
  __shared__ float uS[NH][DD];        // later reused as attq[8][64]
  __shared__ float ctxS[DD], resS[DD];

  const float* Wn = Wqkv + (size_t)n*(3*DD*DD);
  const float* bn = bqkv + (size_t)n*(3*DD);

  if (tid < DD) et[tid] = et_g[n*DD + tid];
  {
    float* a = &attS[0][0];
    for (int i = tid; i < NH*NP; i += 512) a[i] = 0.f;
    float* u = &uS[0][0];
    for (int i = tid; i < NH*DD; i += 512) u[i] = 0.f;
  }
  __syncthreads();

  // P1: q = Wq@et + bq. wave w -> rows [w*32, w*32+32) == head w (no barrier before P2)
  {
    float4 xf[8]; preload8(et, lane, xf);
    #pragma unroll
    for (int pg = 0; pg < 4; ++pg) {
      int r0 = w*32 + pg*8;
      float a = pass8(Wn, DD, r0, lane, xf);
      int r = r0 + (lane >> 3);
      if ((lane & 7) == 0) qv[r] = a + bn[r];
    }
  }
  // P2: t[w][c] = sum_d q[w*32+d] * Wk[w*32+d][c]; qb[w] = q_w . bk_w
  {
    float4 qf[8];
    #pragma unroll
    for (int g = 0; g < 8; ++g) qf[g] = *(const float4*)&qv[w*32 + g*4];
    float qb = 0.f;
    #pragma unroll
    for (int g = 0; g < 8; ++g) {
      float4 bk4 = *(const float4*)&bn[DD + w*32 + g*4];
      qb += dot4(qf[g], bk4);
    }
    if (!lane) qb8[w] = qb;
    float4 acc = make_float4(0.f, 0.f, 0.f, 0.f);
    #pragma unroll
    for (int dg = 0; dg < 4; ++dg) {
      float4 wk[8];
      #pragma unroll
      for (int u = 0; u < 8; ++u)
        wk[u] = *(const float4*)&Wn[(size_t)(DD + w*32 + dg*8 + u)*DD + 4*lane];
      #pragma unroll
      for (int u = 0; u < 8; ++u) {
        float qs = ((const float*)&qf[2*dg + (u >> 2)])[u & 3];
        acc.x += qs*wk[u].x; acc.y += qs*wk[u].y; acc.z += qs*wk[u].z; acc.w += qs*wk[u].w;
      }
    }
    *(float4*)&tS[w][4*lane] = acc;
  }
  __syncthreads();

  // P3: scores (partial over c-half): wave w -> c-half (w>>2), patch quarter (w&3)
  {
    const int chalf = w >> 2, pb = (w & 3)*256;
    float treg[16];
    #pragma unroll
    for (int k = 0; k < 16; ++k) treg[k] = tS[k & 7][chalf*128 + (k >> 3)*64 + lane];
    float4 sacc[8];
    #pragma unroll
    for (int h = 0; h < 8; ++h) sacc[h] = make_float4(0.f,0.f,0.f,0.f);
    const float* pbase = pT + (size_t)(chalf*128)*NP + pb + 4*lane;
    #pragma unroll
    for (int cb = 0; cb < 2; ++cb) {
      #pragma unroll 8
      for (int c0 = 0; c0 < 64; ++c0) {
        float4 pv = *(const float4*)&pbase[(size_t)(cb*64 + c0)*NP];
        #pragma unroll
        for (int h = 0; h < 8; ++h) {
          float tv = rdlane(treg[cb*8 + h], c0);
          sacc[h].x += tv*pv.x; sacc[h].y += tv*pv.y; sacc[h].z += tv*pv.z; sacc[h].w += tv*pv.w;
        }
      }
    }
    #pragma unroll
    for (int h = 0; h < 8; ++h) {
      atomicAdd(&attS[h][pb + 4*lane + 0], sacc[h].x);
      atomicAdd(&attS[h][pb + 4*lane + 1], sacc[h].y);
      atomicAdd(&attS[h][pb + 4*lane + 2], sacc[h].z);
      atomicAdd(&attS[h][pb + 4*lane + 3], sacc[h].w);
    }
  }
  __syncthreads();

  // P4: softmax per head (wave == head); store exp, keep 1/sum
  {
    const int h = w;
    const float qb = qb8[h];
    float v[16];
    #pragma unroll
    for (int k = 0; k < 16; ++k) v[k] = (attS[h][k*64 + lane] + qb) * SCALE;
    float mx = v[0];
    #pragma unroll
    for (int k = 1; k < 16; ++k) mx = fmaxf(mx, v[k]);
    mx = wred_max(mx);
    float sum = 0.f;
    #pragma unroll
    for (int k = 0; k < 16; ++k) {
      v[k] = __expf(v[k] - mx);
      sum += v[k];
      attS[h][k*64 + lane] = v[k];
    }
    sum = wred_sum(sum);
    if (!lane) rinv8[h] = 1.f / sum;
  }
  __syncthreads();

  // P5: iaw head-mean; P6: u[h][c] = sum_p att*patches (8 waves, 128 patches each)
  {
    #pragma unroll
    for (int rep = 0; rep < 2; ++rep) {
      int p = rep*512 + tid;
      float s = 0.f;
      #pragma unroll
      for (int h = 0; h < 8; ++h) s += attS[h][p] * rinv8[h];
      iaw[(size_t)n*NP + p] = s * 0.125f;
    }
    const int pb = w*128;
    float areg[16];
    #pragma unroll
    for (int k = 0; k < 16; ++k)
      areg[k] = attS[k & 7][pb + (k >> 3)*64 + lane] * rinv8[k & 7];
    float4 up[8];
    #pragma unroll
    for (int h = 0; h < 8; ++h) up[h] = make_float4(0.f,0.f,0.f,0.f);
    const float* pbase = patches + (size_t)pb*DD + 4*lane;
    #pragma unroll 4
    for (int p0 = 0; p0 < 128; ++p0) {
      float4 pv = *(const float4*)&pbase[(size_t)p0*DD];
      #pragma unroll
      for (int h = 0; h < 8; ++h) {
        float a = rdlane(areg[(p0 >> 6)*8 + h], p0 & 63);
        up[h].x += a*pv.x; up[h].y += a*pv.y; up[h].z += a*pv.z; up[h].w += a*pv.w;
      }
    }
    #pragma unroll
    for (int h = 0; h < 8; ++h) {
      atomicAdd(&uS[h][4*lane + 0], up[h].x);
      atomicAdd(&uS[h][4*lane + 1], up[h].y);
      atomicAdd(&uS[h][4*lane + 2], up[h].z);
      atomicAdd(&uS[h][4*lane + 3], up[h].w);
    }
  }
  __syncthreads();

  // P7: ctx[r] = u[h(r)] . Wv[r] + bv[r]; wave w rows == head w
  {
    float4 xf[8]; preload8(uS[w], lane, xf);
    #pragma unroll
    for (int pg = 0; pg < 4; ++pg) {
      int r0 = w*32 + pg*8;
      float a = pass8(Wn + (size_t)2*DD*DD, DD, r0, lane, xf);
      int r = r0 + (lane >> 3);
      if ((lane & 7) == 0) ctxS[r] = a + bn[2*DD + r];
    }
  }
  __syncthreads();

  // P8: res = Wo@ctx + bo + et; LN1 -> et (= attended_image row)
  {
    float4 xf[8]; preload8(ctxS, lane, xf);
    const float* Won = Wo + (size_t)n*DD*DD;
    #pragma unroll
    for (int pg = 0; pg < 4; ++pg) {
      int r0 = w*32 + pg*8;
      float a = pass8(Won, DD, r0, lane, xf);
      int r = r0 + (lane >> 3);
      if ((lane & 7) == 0) resS[r] = a + bo[n*DD + r] + et[r];
    }
  }
  layernorm_store(resS, et, ln1g, ln1b, red2, tid, w, lane);
  __syncthreads();

  // ---- query cross attention ----
  {
    float4 xf[8]; preload8(et, lane, xf);
    #pragma unroll
    for (int pg = 0; pg < 4; ++pg) {
      int r0 = w*32 + pg*8;
      float a = pass8(Wqkv_q, DD, r0, lane, xf);
      int r = r0 + (lane >> 3);
      if ((lane & 7) == 0) qv[r] = a + bqkv_q[r];
    }
  }
  float (*attq)[NQ] = (float(*)[NQ])&uS[0][0];
  {
    const int h = w, j = lane;
    float4 q4[8];
    #pragma unroll
    for (int m = 0; m < 8; ++m) q4[m] = *(const float4*)&qv[h*32 + 4*m];
    const float* kj = kvq + (size_t)j*512 + h*32;
    float s = 0.f;
    #pragma unroll
    for (int m = 0; m < 8; ++m) s += dot4(*(const float4*)&kj[4*m], q4[m]);
    s *= SCALE;
    float mx = wred_max(s);
    float p = __expf(s - mx);
    float sum = wred_sum(p);
    attq[h][j] = p / sum;
  }
  __syncthreads();
  if (tid < DD) {
    const int rr = tid, h = rr >> 5;
    float acc = 0.f;
    #pragma unroll 4
    for (int j4 = 0; j4 < 16; ++j4) {
      float4 a4 = *(const float4*)&attq[h][j4*4];
      acc += a4.x * kvq[(size_t)(j4*4+0)*512 + DD + rr]
           + a4.y * kvq[(size_t)(j4*4+1)*512 + DD + rr]
           + a4.z * kvq[(size_t)(j4*4+2)*512 + DD + rr]
           + a4.w * kvq[(size_t)(j4*4+3)*512 + DD + rr];
    }
    ctxS[rr] = acc;
  }
  __syncthreads();
  {
    float4 xf[8]; preload8(ctxS, lane, xf);
    #pragma unroll
    for (int pg = 0; pg < 4; ++pg) {
      int r0 = w*32 + pg*8;
      float a = pass8(Wo_q, DD, r0, lane, xf);
      int r = r0 + (lane >> 3);
      if ((lane & 7) == 0) resS[r] = a + bo_q[r] + et[r];
    }
  }
  layernorm_store(resS, et, ln2g, ln2b, red2, tid, w, lane);  // et = attended_query row
  __syncthreads();

  // ---- FFN1: h = relu(W1@aq + b1), 1024 rows ----
  float* hb = &tS[0][0];
  {
    float4 xf[8]; preload8(et, lane, xf);
    #pragma unroll
    for (int pp = 0; pp < 16; ++pp) {
      int r0 = w*128 + pp*8;
      float a = pass8(W1, DD, r0, lane, xf);
      int r = r0 + (lane >> 3);
      if ((lane & 7) == 0) hb[r] = fmaxf(a + b1[r], 0.f);
    }
  }
  __syncthreads();
  // ---- FFN2: er = W2@h + b2 (K=1024 in 4 chunks) ----
  {
    float accp[4] = {0.f, 0.f, 0.f, 0.f};
    #pragma unroll
    for (int kc = 0; kc < 4; ++kc) {
      float4 xf[8]; preload8(hb + kc*256, lane, xf);
      #pragma unroll
      for (int pg = 0; pg < 4; ++pg) {
        int r0 = w*32 + pg*8;
        const float* base = W2 + (size_t)(r0 + (lane >> 3))*1024 + kc*256 + (lane & 7)*4;
        float4 wv[8];
        #pragma unroll
        for (int cc = 0; cc < 8; ++cc) wv[cc] = *(const float4*)&base[cc*32];
        float a = 0.f;
        #pragma unroll
        for (int cc = 0; cc < 8; ++cc) a += dot4(wv[cc], xf[cc]);
        accp[pg] += a;
      }
    }
    #pragma unroll
    for (int pg = 0; pg < 4; ++pg) {
      float a = red8(accp[pg]);
      int r = w*32 + pg*8 + (lane >> 3);
      if ((lane & 7) == 0) qv[r] = a + b2[r];   // qv = expert_refined row
    }
  }
  __syncthreads();
  // ---- qkv_s projection: 768 rows ----
  float* qrow = &attS[0][0];
  {
    float4 xf[8]; preload8(qv, lane, xf);
    #pragma unroll
    for (int pp = 0; pp < 12; ++pp) {
      int r0 = w*96 + pp*8;
      float a = pass8(Wqkv_s, DD, r0, lane, xf);
      int r = r0 + (lane >> 3);
      if ((lane & 7) == 0) qrow[r] = a + bqkv_s[r];
    }
  }
  __syncthreads();
  for (int idx = tid; idx < 768; idx += 512) qkvs_g[(size_t)n*768 + idx] = qrow[idx];
  if (tid < DD) er_g[(size_t)n*DD + tid] = qv[tid];
}

// ---------------- self attention + LN3 ----------------
__global__ __launch_bounds__(512)
void k_sa(const float* __restrict__ er, const float* __restrict__ qkvs,
          const float* __restrict__ Wo_s, const float* __restrict__ bo_s,
          const float* __restrict__ ln3g, const float* __restrict__ ln3b,
          float* __restrict__ ef)
{
  const int i = blockIdx.x, tid = threadIdx.x, w = tid >> 6, lane = tid & 63;
  __shared__ float x[DD], attl[NH][256], ctxp[2][DD], resS[DD], red2[2];
  if (tid < DD) x[tid] = er[(size_t)i*DD + tid];
  // scores (wave == head)
  {
    const int h = w;
    float4 q4[8];
    #pragma unroll
    for (int m = 0; m < 8; ++m) q4[m] = *(const float4*)&qkvs[(size_t)i*768 + h*32 + 4*m];
    #pragma unroll
    for (int rep = 0; rep < 4; ++rep) {
      int j = lane + 64*rep;
      const float* kj = qkvs + (size_t)j*768 + DD + h*32;
      float4 k4[8];
      #pragma unroll
      for (int m = 0; m < 8; ++m) k4[m] = *(const float4*)&kj[4*m];
      float s = 0.f;
      #pragma unroll
      for (int m = 0; m < 8; ++m) s += dot4(k4[m], q4[m]);
      attl[h][j] = s * SCALE;
    }
  }
  // softmax over 256 keys (same wave wrote these rows)
  {
    const int h = w;
    float v0 = attl[h][lane], v1 = attl[h][lane+64], v2 = attl[h][lane+128], v3 = attl[h][lane+192];
    float mx = wred_max(fmaxf(fmaxf(v0,v1), fmaxf(v2,v3)));
    float e0 = __expf(v0-mx), e1 = __expf(v1-mx), e2 = __expf(v2-mx), e3 = __expf(v3-mx);
    float sum = wred_sum(e0+e1+e2+e3);
    float r = 1.f/sum;
    attl[h][lane] = e0*r; attl[h][lane+64] = e1*r; attl[h][lane+128] = e2*r; attl[h][lane+192] = e3*r;
  }
  __syncthreads();
  // ctx: split the 256-key sum across two thread halves
  {
    const int rr = tid & 255, hf = tid >> 8, h = rr >> 5;
    float acc = 0.f;
    #pragma unroll 4
    for (int j4 = hf*32; j4 < hf*32 + 32; ++j4) {
      float4 a4 = *(const float4*)&attl[h][j4*4];
      acc += a4.x * qkvs[(size_t)(j4*4+0)*768 + 512 + rr]
           + a4.y * qkvs[(size_t)(j4*4+1)*768 + 512 + rr]
           + a4.z * qkvs[(size_t)(j4*4+2)*768 + 512 + rr]
           + a4.w * qkvs[(size_t)(j4*4+3)*768 + 512 + rr];
    }
    ctxp[hf][rr] = acc;
  }
  __syncthreads();
  // out proj + residual + LN3
  {
    float4 xf[8];
    const int o = (lane & 7)*4;
    #pragma unroll
    for (int cc = 0; cc < 8; ++cc) {
      float4 a = *(const float4*)&ctxp[0][cc*32 + o];
      float4 b = *(const float4*)&ctxp[1][cc*32 + o];
      xf[cc] = make_float4(a.x+b.x, a.y+b.y, a.z+b.z, a.w+b.w);
    }
    #pragma unroll
    for (int pg = 0; pg < 4; ++pg) {
      int r0 = w*32 + pg*8;
      float a = pass8(Wo_s, DD, r0, lane, xf);
      int r = r0 + (lane >> 3);
      if ((lane & 7) == 0) resS[r] = a + bo_s[r] + x[r];
    }
  }
  layernorm_store(resS, ef + (size_t)i*DD, ln3g, ln3b, red2, tid, w, lane);
}

extern "C" void kernel_launch(void* const* d_in, const int* in_sizes, int n_in,
                              void* d_out, int out_size, void* d_ws, size_t ws_size,
                              hipStream_t stream) {
  const float* patches = (const float*)d_in[0];
  const float* et      = (const float*)d_in[1];
  const float* qe      = (const float*)d_in[2];
  const float* Wqkv_e  = (const float*)d_in[3];
  const float* bqkv_e  = (const float*)d_in[4];
  const float* Wo_e    = (const float*)d_in[5];
  const float* bo_e    = (const float*)d_in[6];
  const float* Wqkv_q  = (const float*)d_in[7];
  const float* bqkv_q  = (const float*)d_in[8];
  const float* Wo_q    = (const float*)d_in[9];
  const float* bo_q    = (const float*)d_in[10];
  const float* Wqkv_s  = (const float*)d_in[11];
  const float* bqkv_s  = (const float*)d_in[12];
  const float* Wo_s    = (const float*)d_in[13];
  const float* bo_s    = (const float*)d_in[14];
  const float* W1      = (const float*)d_in[15];
  const float* b1      = (const float*)d_in[16];
  const float* W2      = (const float*)d_in[17];
  const float* b2      = (const float*)d_in[18];
  const float* ln1g = (const float*)d_in[19]; const float* ln1b = (const float*)d_in[20];
  const float* ln2g = (const float*)d_in[21]; const float* ln2b = (const float*)d_in[22];
  const float* ln3g = (const float*)d_in[23]; const float* ln3b = (const float*)d_in[24];

  float* ef  = (float*)d_out;               // [256*256] expert_features
  float* iaw = (float*)d_out + 65536;       // [256*1024] image_attention_weights

  float* ws   = (float*)d_ws;
  float* pT   = ws;                   // 262144
  float* kvq  = ws + 262144;          // 32768
  float* er   = ws + 294912;          // 65536
  float* qkvs = ws + 360448;          // 196608

  k_transpose<<<dim3(32, 8), dim3(32, 8), 0, stream>>>(patches, pT);
  k_kvq<<<64, 512, 0, stream>>>(qe, Wqkv_q, bqkv_q, kvq);
  k_fused<<<256, 512, 0, stream>>>(patches, pT, et, Wqkv_e, bqkv_e, Wo_e, bo_e,
                                   kvq, Wqkv_q, bqkv_q, Wo_q, bo_q,
                                   Wqkv_s, bqkv_s, W1, b1, W2, b2,
                                   ln1g, ln1b, ln2g, ln2b,
                                   er, qkvs, iaw);
  k_sa<<<256, 512, 0, stream>>>(er, qkvs, Wo_s, bo_s, ln3g, ln3b, ef);
}

// Round 3
// 186.073 us; speedup vs baseline: 1.6879x; 1.6543x over previous
//
#include <hip/hip_runtime.h>

#define DD 256      // embed dim
#define NH 8        // heads
#define NP 1024     // patches
#define NQ 64       // query embeddings
#define SCALE 0.17677669529663687f

__device__ __forceinline__ float wred_sum(float p) {
  #pragma unroll
  for (int m = 32; m; m >>= 1) p += __shfl_xor(p, m);
  return p;
}
__device__ __forceinline__ float wred_max(float p) {
  #pragma unroll
  for (int m = 32; m; m >>= 1) p = fmaxf(p, __shfl_xor(p, m));
  return p;
}
__device__ __forceinline__ float red8(float p) {
  p += __shfl_xor(p, 1);
  p += __shfl_xor(p, 2);
  p += __shfl_xor(p, 4);
  return p;
}
__device__ __forceinline__ float dot4(float4 a, float4 b) {
  return a.x*b.x + a.y*b.y + a.z*b.z + a.w*b.w;
}
__device__ __forceinline__ void preload8(const float* x, int lane, float4* xf) {
  const int o = (lane & 7) * 4;
  #pragma unroll
  for (int cc = 0; cc < 8; ++cc) xf[cc] = *(const float4*)&x[cc*32 + o];
}
// 16 rows per pass: rows r0+(lane>>3) and r0+8+(lane>>3); 16 loads in flight.
__device__ __forceinline__ void pass16(const float* __restrict__ W, int ldk,
                                       int r0, int lane, const float4* xf,
                                       float* outA, float* outB) {
  const float* baseA = W + (size_t)(r0 + (lane >> 3))*ldk + (lane & 7)*4;
  const float* baseB = baseA + (size_t)8*ldk;
  float4 wa[8], wb[8];
  #pragma unroll
  for (int cc = 0; cc < 8; ++cc) wa[cc] = *(const float4*)&baseA[cc*32];
  #pragma unroll
  for (int cc = 0; cc < 8; ++cc) wb[cc] = *(const float4*)&baseB[cc*32];
  float a = 0.f, b = 0.f;
  #pragma unroll
  for (int cc = 0; cc < 8; ++cc) { a += dot4(wa[cc], xf[cc]); b += dot4(wb[cc], xf[cc]); }
  *outA = red8(a); *outB = red8(b);
}

// layernorm over a 256-float LDS buffer -> outp (LDS or global)
__device__ __forceinline__ void layernorm_store(const float* buf, float* outp,
                                                const float* g, const float* b,
                                                float* red, int tid, int wid, int lane)
{
  __syncthreads();
  if (wid == 0) {
    float s = buf[lane] + buf[lane+64] + buf[lane+128] + buf[lane+192];
    s = wred_sum(s);
    if (!lane) red[0] = s * (1.f/256.f);
  }
  __syncthreads();
  float mn = red[0];
  if (wid == 0) {
    float d0 = buf[lane]-mn, d1 = buf[lane+64]-mn, d2 = buf[lane+128]-mn, d3 = buf[lane+192]-mn;
    float s = d0*d0 + d1*d1 + d2*d2 + d3*d3;
    s = wred_sum(s);
    if (!lane) red[1] = rsqrtf(s * (1.f/256.f) + 1e-5f);
  }
  __syncthreads();
  if (tid < 256) outp[tid] = (buf[tid] - mn) * red[1] * g[tid] + b[tid];
}

// ---------------- patches transpose ----------------
__global__ __launch_bounds__(256)
void k_transpose(const float* __restrict__ in, float* __restrict__ out)
{
  __shared__ float tile[32][33];
  const int pb = blockIdx.x*32, cb = blockIdx.y*32;
  const int tx = threadIdx.x, ty = threadIdx.y;
  #pragma unroll
  for (int i = 0; i < 4; ++i)
    tile[ty + i*8][tx] = in[(size_t)(pb + ty + i*8)*DD + cb + tx];
  __syncthreads();
  #pragma unroll
  for (int i = 0; i < 4; ++i)
    out[(size_t)(cb + ty + i*8)*NP + pb + tx] = tile[tx][ty + i*8];
}

// ---------------- K/V projection of query_embeddings ----------------
__global__ __launch_bounds__(512)
void k_kvq(const float* __restrict__ qe, const float* __restrict__ Wqkv_q,
           const float* __restrict__ bqkv_q, float* __restrict__ kvq)
{
  const int j = blockIdx.x, tid = threadIdx.x, w = tid>>6, lane = tid&63;
  __shared__ float x[DD], kvrow[512];
  if (tid < DD) x[tid] = qe[j*DD + tid];
  __syncthreads();
  float4 xf[8]; preload8(x, lane, xf);
  #pragma unroll
  for (int g = 0; g < 4; ++g) {
    int r0 = w*64 + g*16;
    float a, b;
    pass16(Wqkv_q + (size_t)DD*DD, DD, r0, lane, xf, &a, &b);
    int rA = r0 + (lane >> 3);
    if ((lane & 7) == 0) { kvrow[rA] = a + bqkv_q[DD + rA]; kvrow[rA+8] = b + bqkv_q[DD + rA + 8]; }
  }
  __syncthreads();
  kvq[(size_t)j*512 + tid] = kvrow[tid];
}

// ---------------- q projection + t = q_h^T Wk_h  (streams Wq, Wk: 134 MB) ----------------
__global__ __launch_bounds__(512)
void k_qt(const float* __restrict__ et_g, const float* __restrict__ Wqkv,
          const float* __restrict__ bqkv, float* __restrict__ t_ws)
{
  const int n = blockIdx.x, tid = threadIdx.x, w = tid>>6, lane = tid&63;
  __shared__ float xL[DD], qL[DD];
  if (tid < DD) xL[tid] = et_g[n*DD + tid];
  __syncthreads();
  const float* Wn = Wqkv + (size_t)n*(3*DD*DD);
  const float* bn = bqkv + (size_t)n*(3*DD);
  // q-phase: 8 waves x 32 rows
  {
    float4 xf[8]; preload8(xL, lane, xf);
    #pragma unroll
    for (int g = 0; g < 2; ++g) {
      int r0 = w*32 + g*16;
      float a, b;
      pass16(Wn, DD, r0, lane, xf, &a, &b);
      int rA = r0 + (lane >> 3);
      if ((lane & 7) == 0) { qL[rA] = a + bn[rA]; qL[rA+8] = b + bn[rA+8]; }
    }
  }
  __syncthreads();
  // t-phase: wave = head; t[h][c] = sum_d q[h*32+d] * Wk[h*32+d][c]
  {
    const float* Wk = Wn + (size_t)DD*DD + (size_t)w*32*DD;
    float4 acc = make_float4(0.f,0.f,0.f,0.f);
    #pragma unroll
    for (int dc = 0; dc < 8; ++dc) {
      float4 q4 = *(const float4*)&qL[w*32 + dc*4];
      float4 r0v = *(const float4*)&Wk[(size_t)(dc*4+0)*DD + 4*lane];
      float4 r1v = *(const float4*)&Wk[(size_t)(dc*4+1)*DD + 4*lane];
      float4 r2v = *(const float4*)&Wk[(size_t)(dc*4+2)*DD + 4*lane];
      float4 r3v = *(const float4*)&Wk[(size_t)(dc*4+3)*DD + 4*lane];
      acc.x += q4.x*r0v.x + q4.y*r1v.x + q4.z*r2v.x + q4.w*r3v.x;
      acc.y += q4.x*r0v.y + q4.y*r1v.y + q4.z*r2v.y + q4.w*r3v.y;
      acc.z += q4.x*r0v.z + q4.y*r1v.z + q4.z*r2v.z + q4.w*r3v.z;
      acc.w += q4.x*r0v.w + q4.y*r1v.w + q4.z*r2v.w + q4.w*r3v.w;
    }
    *(float4*)&t_ws[(size_t)n*2048 + w*256 + 4*lane] = acc;
  }
}

// ---------------- scores + softmax + iaw + u  (L2-resident pT/patches, f32 ALU) -------------
__global__ __launch_bounds__(512)
void k_scores(const float* __restrict__ pT, const float* __restrict__ patches,
              const float* __restrict__ t_ws, float* __restrict__ u_ws,
              float* __restrict__ iaw)
{
  const int n = blockIdx.x, tid = threadIdx.x, w = tid>>6, lane = tid&63;
  __shared__ float tS[NH][DD];       // 8 KB
  __shared__ float attS[NH][NP];     // 32 KB
  __shared__ float up[2][NH][DD];    // 16 KB
  ((float4*)&tS[0][0])[tid] = ((const float4*)(t_ws + (size_t)n*2048))[tid];
  __syncthreads();
  // S-phase: thread owns patches 2*tid, 2*tid+1
  {
    float acc[NH][2];
    #pragma unroll
    for (int h = 0; h < NH; ++h) { acc[h][0] = 0.f; acc[h][1] = 0.f; }
    #pragma unroll 2
    for (int c4 = 0; c4 < 64; ++c4) {
      float2 pv[4];
      #pragma unroll
      for (int j = 0; j < 4; ++j)
        pv[j] = *(const float2*)&pT[(size_t)(c4*4+j)*NP + 2*tid];
      #pragma unroll
      for (int h = 0; h < NH; ++h) {
        float4 t4 = *(const float4*)&tS[h][c4*4];
        acc[h][0] += t4.x*pv[0].x + t4.y*pv[1].x + t4.z*pv[2].x + t4.w*pv[3].x;
        acc[h][1] += t4.x*pv[0].y + t4.y*pv[1].y + t4.z*pv[2].y + t4.w*pv[3].y;
      }
    }
    #pragma unroll
    for (int h = 0; h < NH; ++h) {
      attS[h][2*tid]   = acc[h][0];
      attS[h][2*tid+1] = acc[h][1];
    }
  }
  __syncthreads();
  // softmax (wave == head), store normalized probabilities
  {
    const int h = w;
    float v[16];
    #pragma unroll
    for (int k = 0; k < 16; ++k) v[k] = attS[h][k*64 + lane] * SCALE;
    float mx = v[0];
    #pragma unroll
    for (int k = 1; k < 16; ++k) mx = fmaxf(mx, v[k]);
    mx = wred_max(mx);
    float sum = 0.f;
    #pragma unroll
    for (int k = 0; k < 16; ++k) { v[k] = __expf(v[k] - mx); sum += v[k]; }
    sum = wred_sum(sum);
    float rinv = 1.f / sum;
    #pragma unroll
    for (int k = 0; k < 16; ++k) attS[h][k*64 + lane] = v[k] * rinv;
  }
  __syncthreads();
  // iaw: head-mean
  #pragma unroll
  for (int rep = 0; rep < 2; ++rep) {
    int p = rep*512 + tid;
    float s = 0.f;
    #pragma unroll
    for (int h = 0; h < NH; ++h) s += attS[h][p];
    iaw[(size_t)n*NP + p] = s * 0.125f;
  }
  // u-phase: split-k over patch halves; wave-group ph owns 512 patches, 4 waves cover 256 cols
  {
    const int ph = w >> 2, c = (w & 3)*64 + lane;
    float ua[NH];
    #pragma unroll
    for (int h = 0; h < NH; ++h) ua[h] = 0.f;
    const float* pb = patches + (size_t)ph*512*DD + c;
    #pragma unroll 2
    for (int pc = 0; pc < 128; ++pc) {
      float p0 = pb[(size_t)(pc*4+0)*DD];
      float p1 = pb[(size_t)(pc*4+1)*DD];
      float p2 = pb[(size_t)(pc*4+2)*DD];
      float p3 = pb[(size_t)(pc*4+3)*DD];
      #pragma unroll
      for (int h = 0; h < NH; ++h) {
        float4 a4 = *(const float4*)&attS[h][ph*512 + pc*4];
        ua[h] += a4.x*p0 + a4.y*p1 + a4.z*p2 + a4.w*p3;
      }
    }
    #pragma unroll
    for (int h = 0; h < NH; ++h) up[ph][h][c] = ua[h];
  }
  __syncthreads();
  if (tid < DD) {
    #pragma unroll
    for (int h = 0; h < NH; ++h)
      u_ws[(size_t)n*2048 + h*256 + tid] = up[0][h][tid] + up[1][h][tid];
  }
}

// ---------------- ctx = u @ Wv^T + bv ; out = ctx @ Wo^T + bo + et ; LN1 (streams Wv, Wo) ----
__global__ __launch_bounds__(512)
void k_ctxout(const float* __restrict__ u_ws, const float* __restrict__ et_g,
              const float* __restrict__ Wqkv, const float* __restrict__ bqkv,
              const float* __restrict__ Wo, const float* __restrict__ bo,
              const float* __restrict__ ln1g, const float* __restrict__ ln1b,
              float* __restrict__ aln)
{
  const int n = blockIdx.x, tid = threadIdx.x, w = tid>>6, lane = tid&63;
  __shared__ float uL[NH][DD], ctxL[DD], resS[DD], red2[2];
  ((float4*)&uL[0][0])[tid] = ((const float4*)(u_ws + (size_t)n*2048))[tid];
  __syncthreads();
  const float* Wn = Wqkv + (size_t)n*(3*DD*DD);
  const float* bn = bqkv + (size_t)n*(3*DD);
  // ctx: wave = head; rows w*32..+32 of Wv
  {
    float4 xf[8]; preload8(&uL[w][0], lane, xf);
    #pragma unroll
    for (int g = 0; g < 2; ++g) {
      int r0 = w*32 + g*16;
      float a, b;
      pass16(Wn + (size_t)2*DD*DD, DD, r0, lane, xf, &a, &b);
      int rA = r0 + (lane >> 3);
      if ((lane & 7) == 0) { ctxL[rA] = a + bn[2*DD + rA]; ctxL[rA+8] = b + bn[2*DD + rA + 8]; }
    }
  }
  __syncthreads();
  // out proj + residual
  {
    float4 xf[8]; preload8(ctxL, lane, xf);
    const float* Won = Wo + (size_t)n*DD*DD;
    #pragma unroll
    for (int g = 0; g < 2; ++g) {
      int r0 = w*32 + g*16;
      float a, b;
      pass16(Won, DD, r0, lane, xf, &a, &b);
      int rA = r0 + (lane >> 3);
      if ((lane & 7) == 0) {
        resS[rA]   = a + bo[n*DD + rA]     + et_g[(size_t)n*DD + rA];
        resS[rA+8] = b + bo[n*DD + rA + 8] + et_g[(size_t)n*DD + rA + 8];
      }
    }
  }
  layernorm_store(resS, aln + (size_t)n*DD, ln1g, ln1b, red2, tid, w, lane);
}

// ---------------- tail: qca + LN2 + FFN + qkv_s projection ----------------
__global__ __launch_bounds__(512)
void k_tail(const float* __restrict__ aln, const float* __restrict__ kvq,
            const float* __restrict__ Wqkv_q, const float* __restrict__ bqkv_q,
            const float* __restrict__ Wo_q, const float* __restrict__ bo_q,
            const float* __restrict__ W1, const float* __restrict__ b1,
            const float* __restrict__ W2, const float* __restrict__ b2,
            const float* __restrict__ Wqkv_s, const float* __restrict__ bqkv_s,
            const float* __restrict__ ln2g, const float* __restrict__ ln2b,
            float* __restrict__ er_g, float* __restrict__ qkvs_g)
{
  const int i = blockIdx.x, tid = threadIdx.x, w = tid>>6, lane = tid&63;
  __shared__ float xL[DD], qv[DD], attq[NH][NQ], ctxS[DD], resS[DD], red2[2];
  __shared__ float hb[1024], qrow[768];
  if (tid < DD) xL[tid] = aln[(size_t)i*DD + tid];
  __syncthreads();
  // q projection
  {
    float4 xf[8]; preload8(xL, lane, xf);
    #pragma unroll
    for (int g = 0; g < 2; ++g) {
      int r0 = w*32 + g*16;
      float a, b;
      pass16(Wqkv_q, DD, r0, lane, xf, &a, &b);
      int rA = r0 + (lane >> 3);
      if ((lane & 7) == 0) { qv[rA] = a + bqkv_q[rA]; qv[rA+8] = b + bqkv_q[rA+8]; }
    }
  }
  __syncthreads();
  // attention over 64 kv (wave == head, lane == j)
  {
    const int h = w, j = lane;
    float4 q4[8];
    #pragma unroll
    for (int m = 0; m < 8; ++m) q4[m] = *(const float4*)&qv[h*32 + 4*m];
    const float* kj = kvq + (size_t)j*512 + h*32;
    float s = 0.f;
    #pragma unroll
    for (int m = 0; m < 8; ++m) s += dot4(*(const float4*)&kj[4*m], q4[m]);
    s *= SCALE;
    float mx = wred_max(s);
    float p = __expf(s - mx);
    float sum = wred_sum(p);
    attq[h][j] = p / sum;
  }
  __syncthreads();
  if (tid < DD) {
    const int rr = tid, h = rr >> 5;
    float acc = 0.f;
    #pragma unroll 4
    for (int j4 = 0; j4 < 16; ++j4) {
      float4 a4 = *(const float4*)&attq[h][j4*4];
      acc += a4.x * kvq[(size_t)(j4*4+0)*512 + DD + rr]
           + a4.y * kvq[(size_t)(j4*4+1)*512 + DD + rr]
           + a4.z * kvq[(size_t)(j4*4+2)*512 + DD + rr]
           + a4.w * kvq[(size_t)(j4*4+3)*512 + DD + rr];
    }
    ctxS[rr] = acc;
  }
  __syncthreads();
  // out proj + residual + LN2 -> xL
  {
    float4 xf[8]; preload8(ctxS, lane, xf);
    #pragma unroll
    for (int g = 0; g < 2; ++g) {
      int r0 = w*32 + g*16;
      float a, b;
      pass16(Wo_q, DD, r0, lane, xf, &a, &b);
      int rA = r0 + (lane >> 3);
      if ((lane & 7) == 0) { resS[rA] = a + bo_q[rA] + xL[rA]; resS[rA+8] = b + bo_q[rA+8] + xL[rA+8]; }
    }
  }
  layernorm_store(resS, xL, ln2g, ln2b, red2, tid, w, lane);
  __syncthreads();
  // FFN1
  {
    float4 xf[8]; preload8(xL, lane, xf);
    #pragma unroll
    for (int g = 0; g < 8; ++g) {
      int r0 = w*128 + g*16;
      float a, b;
      pass16(W1, DD, r0, lane, xf, &a, &b);
      int rA = r0 + (lane >> 3);
      if ((lane & 7) == 0) { hb[rA] = fmaxf(a + b1[rA], 0.f); hb[rA+8] = fmaxf(b + b1[rA+8], 0.f); }
    }
  }
  __syncthreads();
  // FFN2 (K = 1024 in 4 chunks)
  {
    float accA[2] = {0.f, 0.f}, accB[2] = {0.f, 0.f};
    #pragma unroll
    for (int kc = 0; kc < 4; ++kc) {
      float4 xh[8]; preload8(hb + kc*256, lane, xh);
      #pragma unroll
      for (int g = 0; g < 2; ++g) {
        float a, b;
        pass16(W2 + kc*256, 1024, w*32 + g*16, lane, xh, &a, &b);
        accA[g] += a; accB[g] += b;
      }
    }
    #pragma unroll
    for (int g = 0; g < 2; ++g) {
      int rA = w*32 + g*16 + (lane >> 3);
      if ((lane & 7) == 0) { qv[rA] = accA[g] + b2[rA]; qv[rA+8] = accB[g] + b2[rA+8]; }
    }
  }
  __syncthreads();
  // qkv_s projection (768 rows)
  {
    float4 xf[8]; preload8(qv, lane, xf);
    #pragma unroll
    for (int g = 0; g < 6; ++g) {
      int r0 = w*96 + g*16;
      float a, b;
      pass16(Wqkv_s, DD, r0, lane, xf, &a, &b);
      int rA = r0 + (lane >> 3);
      if ((lane & 7) == 0) { qrow[rA] = a + bqkv_s[rA]; qrow[rA+8] = b + bqkv_s[rA+8]; }
    }
  }
  __syncthreads();
  for (int idx = tid; idx < 768; idx += 512) qkvs_g[(size_t)i*768 + idx] = qrow[idx];
  if (tid < DD) er_g[(size_t)i*DD + tid] = qv[tid];
}

// ---------------- self attention + LN3 ----------------
__global__ __launch_bounds__(512)
void k_sa(const float* __restrict__ er, const float* __restrict__ qkvs,
          const float* __restrict__ Wo_s, const float* __restrict__ bo_s,
          const float* __restrict__ ln3g, const float* __restrict__ ln3b,
          float* __restrict__ ef)
{
  const int i = blockIdx.x, tid = threadIdx.x, w = tid >> 6, lane = tid & 63;
  __shared__ float x[DD], attl[NH][256], ctxp[2][DD], resS[DD], red2[2];
  if (tid < DD) x[tid] = er[(size_t)i*DD + tid];
  {
    const int h = w;
    float4 q4[8];
    #pragma unroll
    for (int m = 0; m < 8; ++m) q4[m] = *(const float4*)&qkvs[(size_t)i*768 + h*32 + 4*m];
    #pragma unroll
    for (int rep = 0; rep < 4; ++rep) {
      int j = lane + 64*rep;
      const float* kj = qkvs + (size_t)j*768 + DD + h*32;
      float4 k4[8];
      #pragma unroll
      for (int m = 0; m < 8; ++m) k4[m] = *(const float4*)&kj[4*m];
      float s = 0.f;
      #pragma unroll
      for (int m = 0; m < 8; ++m) s += dot4(k4[m], q4[m]);
      attl[h][j] = s * SCALE;
    }
  }
  {
    const int h = w;
    float v0 = attl[h][lane], v1 = attl[h][lane+64], v2 = attl[h][lane+128], v3 = attl[h][lane+192];
    float mx = wred_max(fmaxf(fmaxf(v0,v1), fmaxf(v2,v3)));
    float e0 = __expf(v0-mx), e1 = __expf(v1-mx), e2 = __expf(v2-mx), e3 = __expf(v3-mx);
    float sum = wred_sum(e0+e1+e2+e3);
    float r = 1.f/sum;
    attl[h][lane] = e0*r; attl[h][lane+64] = e1*r; attl[h][lane+128] = e2*r; attl[h][lane+192] = e3*r;
  }
  __syncthreads();
  {
    const int rr = tid & 255, hf = tid >> 8, h = rr >> 5;
    float acc = 0.f;
    #pragma unroll 4
    for (int j4 = hf*32; j4 < hf*32 + 32; ++j4) {
      float4 a4 = *(const float4*)&attl[h][j4*4];
      acc += a4.x * qkvs[(size_t)(j4*4+0)*768 + 512 + rr]
           + a4.y * qkvs[(size_t)(j4*4+1)*768 + 512 + rr]
           + a4.z * qkvs[(size_t)(j4*4+2)*768 + 512 + rr]
           + a4.w * qkvs[(size_t)(j4*4+3)*768 + 512 + rr];
    }
    ctxp[hf][rr] = acc;
  }
  __syncthreads();
  {
    float4 xf[8];
    const int o = (lane & 7)*4;
    #pragma unroll
    for (int cc = 0; cc < 8; ++cc) {
      float4 a = *(const float4*)&ctxp[0][cc*32 + o];
      float4 b = *(const float4*)&ctxp[1][cc*32 + o];
      xf[cc] = make_float4(a.x+b.x, a.y+b.y, a.z+b.z, a.w+b.w);
    }
    #pragma unroll
    for (int g = 0; g < 2; ++g) {
      int r0 = w*32 + g*16;
      float a, b;
      pass16(Wo_s, DD, r0, lane, xf, &a, &b);
      int rA = r0 + (lane >> 3);
      if ((lane & 7) == 0) { resS[rA] = a + bo_s[rA] + x[rA]; resS[rA+8] = b + bo_s[rA+8] + x[rA+8]; }
    }
  }
  layernorm_store(resS, ef + (size_t)i*DD, ln3g, ln3b, red2, tid, w, lane);
}

extern "C" void kernel_launch(void* const* d_in, const int* in_sizes, int n_in,
                              void* d_out, int out_size, void* d_ws, size_t ws_size,
                              hipStream_t stream) {
  const float* patches = (const float*)d_in[0];
  const float* et      = (const float*)d_in[1];
  const float* qe      = (const float*)d_in[2];
  const float* Wqkv_e  = (const float*)d_in[3];
  const float* bqkv_e  = (const float*)d_in[4];
  const float* Wo_e    = (const float*)d_in[5];
  const float* bo_e    = (const float*)d_in[6];
  const float* Wqkv_q  = (const float*)d_in[7];
  const float* bqkv_q  = (const float*)d_in[8];
  const float* Wo_q    = (const float*)d_in[9];
  const float* bo_q    = (const float*)d_in[10];
  const float* Wqkv_s  = (const float*)d_in[11];
  const float* bqkv_s  = (const float*)d_in[12];
  const float* Wo_s    = (const float*)d_in[13];
  const float* bo_s    = (const float*)d_in[14];
  const float* W1      = (const float*)d_in[15];
  const float* b1      = (const float*)d_in[16];
  const float* W2      = (const float*)d_in[17];
  const float* b2      = (const float*)d_in[18];
  const float* ln1g = (const float*)d_in[19]; const float* ln1b = (const float*)d_in[20];
  const float* ln2g = (const float*)d_in[21]; const float* ln2b = (const float*)d_in[22];
  const float* ln3g = (const float*)d_in[23]; const float* ln3b = (const float*)d_in[24];

  float* ef  = (float*)d_out;
  float* iaw = (float*)d_out + 65536;

  float* ws   = (float*)d_ws;
  float* pT   = ws;                   // 262144 floats
  float* kvq  = ws + 262144;          // 32768
  float* t_u  = ws + 294912;          // 524288 (t, later aliased as u)
  float* aln  = ws + 819200;          // 65536
  float* er   = ws + 884736;          // 65536
  float* qkvs = ws + 950272;          // 196608

  k_transpose<<<dim3(32, 8), dim3(32, 8), 0, stream>>>(patches, pT);
  k_kvq<<<64, 512, 0, stream>>>(qe, Wqkv_q, bqkv_q, kvq);
  k_qt<<<256, 512, 0, stream>>>(et, Wqkv_e, bqkv_e, t_u);
  k_scores<<<256, 512, 0, stream>>>(pT, patches, t_u, t_u, iaw);
  k_ctxout<<<256, 512, 0, stream>>>(t_u, et, Wqkv_e, bqkv_e, Wo_e, bo_e, ln1g, ln1b, aln);
  k_tail<<<256, 512, 0, stream>>>(aln, kvq, Wqkv_q, bqkv_q, Wo_q, bo_q,
                                  W1, b1, W2, b2, Wqkv_s, bqkv_s, ln2g, ln2b, er, qkvs);
  k_sa<<<256, 512, 0, stream>>>(er, qkvs, Wo_s, bo_s, ln3g, ln3b, ef);
}